// Round 15
// baseline (145.226 us; speedup 1.0000x reference)
//
#include <hip/hip_runtime.h>
#include <stdint.h>

#define NN 100000
#define EE 1250000
#define NBUCK 196          // ceil(NN/512)
#define CHUNK 4096
#define NCHUNK ((EE + CHUNK - 1) / CHUNK)  // 306
#define PSLICE 24          // pooling slices per graph
#define XB_NB ((NN * 64 / 4 + 255) / 256)  // 6250

typedef __attribute__((ext_vector_type(8))) short short8;
typedef __attribute__((ext_vector_type(4))) float f32x4;

__device__ inline ushort f2bf(float f) {
  union { float f; uint32_t u; } v; v.f = f;
  uint32_t r = v.u + 0x7FFF + ((v.u >> 16) & 1);
  return (ushort)(r >> 16);
}
__device__ inline float bf2f(ushort h) {
  union { uint32_t u; float f; } v; v.u = ((uint32_t)h) << 16;
  return v.f;
}

// ---------------- merged front: weight frags | x->bf16 | per-chunk histogram ----------
__global__ __launch_bounds__(256) void kfront(const float* __restrict__ w1_rel,
                                              const float* __restrict__ w1_root,
                                              const float* __restrict__ w2_rel,
                                              const float* __restrict__ w2_root,
                                              const float* __restrict__ x,
                                              const int* __restrict__ dstI,
                                              ushort* __restrict__ WF,
                                              ushort* __restrict__ xb,
                                              int* __restrict__ histG) {
  __shared__ int h[NBUCK];
  int t = threadIdx.x;
  int blk = blockIdx.x;
  if (blk < 32) {
    int idx = blk * 256 + t;
    if (idx < 8192) {
      int j = idx & 7, l = (idx >> 3) & 63, ts = idx >> 9;
      {
        int s = ts & 1, tt = ts >> 1;
        int o = tt * 16 + (l & 15), k = s * 32 + (l >> 4) * 8 + j;
        WF[idx] = f2bf(w1_rel[o * 64 + k]);
        WF[8192 + idx] = f2bf(w1_root[o * 64 + k]);
      }
      {
        int s = ts & 3, tt = ts >> 2;
        int o = tt * 16 + (l & 15), k = s * 32 + (l >> 4) * 8 + j;
        WF[16384 + idx] = f2bf(w2_rel[o * 128 + k]);
        WF[24576 + idx] = f2bf(w2_root[o * 128 + k]);
      }
    }
  } else if (blk < 32 + XB_NB) {
    int i = ((blk - 32) * 256 + t) * 4;
    if (i < NN * 64) {
      float4 v = *reinterpret_cast<const float4*>(x + i);
      ushort o[4] = {f2bf(v.x), f2bf(v.y), f2bf(v.z), f2bf(v.w)};
      *reinterpret_cast<uint2*>(xb + i) = *reinterpret_cast<uint2*>(o);
    }
  } else {
    int c = blk - 32 - XB_NB;  // chunk id
    if (t < NBUCK) h[t] = 0;
    __syncthreads();
    int cb = c * CHUNK;
    int cc = EE - cb; if (cc > CHUNK) cc = CHUNK;
    for (int i = t; i < cc; i += 256) atomicAdd(&h[dstI[cb + i] >> 9], 1);
    __syncthreads();
    if (t < NBUCK) histG[c * NBUCK + t] = h[t];
  }
}

// ---------------- 2D scan: for each bucket, exclusive scan over chunks ----------------
__global__ __launch_bounds__(512) void kscan2d(const int* __restrict__ histG,
                                               int* __restrict__ relG,
                                               int* __restrict__ bucketTotal) {
  __shared__ int sm[512];
  int b = blockIdx.x;
  int t = threadIdx.x;
  int v = (t < NCHUNK) ? histG[t * NBUCK + b] : 0;
  sm[t] = v;
  __syncthreads();
  for (int d = 1; d < 512; d <<= 1) {
    int u = (t >= d) ? sm[t - d] : 0;
    __syncthreads();
    sm[t] += u;
    __syncthreads();
  }
  if (t < NCHUNK) relG[t * NBUCK + b] = sm[t] - v;
  if (t == 511) bucketTotal[b] = sm[511];
}

// ---------------- binning pass 2: local bucketStart scan + LDS reorder + run copy ----
__global__ __launch_bounds__(256) void kbinA2(const int* __restrict__ srcI,
                                              const int* __restrict__ dstI,
                                              const int* __restrict__ histG,
                                              const int* __restrict__ relG,
                                              const int* __restrict__ bucketTotal,
                                              uint32_t* __restrict__ pairsG) {
  __shared__ uint32_t pko[CHUNK];       // 16 KB
  __shared__ int ss[256];
  __shared__ int bsL[NBUCK];
  __shared__ int ex[NBUCK + 1];
  __shared__ int cur[NBUCK];
  __shared__ int gb[NBUCK];
  int t = threadIdx.x;
  int cb = blockIdx.x * CHUNK;
  int cc = EE - cb; if (cc > CHUNK) cc = CHUNK;

  {
    int bv = (t < NBUCK) ? bucketTotal[t] : 0;
    ss[t] = bv;
    __syncthreads();
    for (int d = 1; d < 256; d <<= 1) {
      int u = (t >= d) ? ss[t - d] : 0;
      __syncthreads();
      ss[t] += u;
      __syncthreads();
    }
    if (t < NBUCK) bsL[t] = ss[t] - bv;
    __syncthreads();
  }
  int v = (t < NBUCK) ? histG[blockIdx.x * NBUCK + t] : 0;
  ss[t] = v;
  __syncthreads();
  for (int d = 1; d < 256; d <<= 1) {
    int u = (t >= d) ? ss[t - d] : 0;
    __syncthreads();
    ss[t] += u;
    __syncthreads();
  }
  if (t < NBUCK) {
    ex[t] = ss[t] - v;
    cur[t] = ss[t] - v;
    gb[t] = bsL[t] + relG[blockIdx.x * NBUCK + t];
  }
  if (t == NBUCK - 1) ex[NBUCK] = ss[t];
  __syncthreads();
  for (int i = t; i < cc; i += 256) {
    int d = dstI[cb + i];
    int s = srcI[cb + i];
    int b = d >> 9;
    int p = atomicAdd(&cur[b], 1);
    pko[p] = (uint32_t)s | ((uint32_t)(d & 511) << 17);
  }
  __syncthreads();
  if (t < NBUCK) {
    int base = ex[t], cnt = ex[t + 1] - base, g0 = gb[t];
    for (int j = 0; j < cnt; ++j) pairsG[g0 + j] = pko[base + j];
  }
}

// ---------------- pass B: per-bucket node-level CSR (starts + esrc) ----------------
__global__ __launch_bounds__(256) void kbinB(const uint32_t* __restrict__ pairsG,
                                             const int* __restrict__ bucketTotal,
                                             int* __restrict__ starts,
                                             int* __restrict__ esrc) {
  __shared__ int hist[512];
  __shared__ int ex2[512];
  __shared__ int part[256];
  __shared__ int baseS;
  int t = threadIdx.x;
  int b = blockIdx.x;
  int nbase = b << 9;
  {
    int bv = (t < NBUCK) ? bucketTotal[t] : 0;
    part[t] = bv;
    __syncthreads();
    for (int d = 1; d < 256; d <<= 1) {
      int u = (t >= d) ? part[t - d] : 0;
      __syncthreads();
      part[t] += u;
      __syncthreads();
    }
    if (t == b) baseS = part[t] - bv;
    __syncthreads();
  }
  int base = baseS;
  int ecnt = bucketTotal[b];

  hist[t] = 0; hist[t + 256] = 0;
  __syncthreads();
  for (int i = t; i < ecnt; i += 256) atomicAdd(&hist[pairsG[base + i] >> 17], 1);
  __syncthreads();
  int a = hist[2 * t], c = hist[2 * t + 1];
  part[t] = a + c;
  __syncthreads();
  for (int d = 1; d < 256; d <<= 1) {
    int u = (t >= d) ? part[t - d] : 0;
    __syncthreads();
    part[t] += u;
    __syncthreads();
  }
  int pex = part[t] - (a + c);
  ex2[2 * t] = pex;
  ex2[2 * t + 1] = pex + a;
  __syncthreads();
  for (int n = t; n < 512; n += 256) {
    int node = nbase + n;
    if (node < NN) starts[node] = base + ex2[n];
  }
  if (b == NBUCK - 1 && t == 0) starts[NN] = EE;
  for (int n = t; n < 512; n += 256) hist[n] = ex2[n];
  __syncthreads();
  for (int i = t; i < ecnt; i += 256) {
    uint32_t p = pairsG[base + i];
    int dl = p >> 17;
    int s = p & 0x1FFFF;
    int lp = atomicAdd(&hist[dl], 1);
    esrc[base + lp] = s;
  }
}

// ---------------- 8-lane-per-node gather core: 16B loads, 8-deep pipeline ----------------
#define ACC8(u)                                                                    \
  a0 += bf2f((ushort)(u).x); a1 += bf2f((ushort)((u).x >> 16));                    \
  a2 += bf2f((ushort)(u).y); a3 += bf2f((ushort)((u).y >> 16));                    \
  a4 += bf2f((ushort)(u).z); a5 += bf2f((ushort)((u).z >> 16));                    \
  a6 += bf2f((ushort)(u).w); a7 += bf2f((ushort)((u).w >> 16));

#define GATHER_CORE8(featb)                                                        \
  const ushort* fb = (featb) + 8 * lg;                                             \
  int i = b;                                                                       \
  {                                                                                \
    int s0 = 0, s1 = 0, s2 = 0, s3 = 0, s4 = 0, s5 = 0, s6 = 0, s7 = 0;            \
    bool have = (i + 8 <= e);                                                      \
    if (have) {                                                                    \
      s0 = esrc[i];     s1 = esrc[i + 1]; s2 = esrc[i + 2]; s3 = esrc[i + 3];      \
      s4 = esrc[i + 4]; s5 = esrc[i + 5]; s6 = esrc[i + 6]; s7 = esrc[i + 7];      \
    }                                                                              \
    while (have) {                                                                 \
      uint4 u0 = *(const uint4*)(fb + (size_t)s0 * 64);                            \
      uint4 u1 = *(const uint4*)(fb + (size_t)s1 * 64);                            \
      uint4 u2 = *(const uint4*)(fb + (size_t)s2 * 64);                            \
      uint4 u3 = *(const uint4*)(fb + (size_t)s3 * 64);                            \
      uint4 u4 = *(const uint4*)(fb + (size_t)s4 * 64);                            \
      uint4 u5 = *(const uint4*)(fb + (size_t)s5 * 64);                            \
      uint4 u6 = *(const uint4*)(fb + (size_t)s6 * 64);                            \
      uint4 u7 = *(const uint4*)(fb + (size_t)s7 * 64);                            \
      i += 8;                                                                      \
      have = (i + 8 <= e);                                                         \
      if (have) {                                                                  \
        s0 = esrc[i];     s1 = esrc[i + 1]; s2 = esrc[i + 2]; s3 = esrc[i + 3];    \
        s4 = esrc[i + 4]; s5 = esrc[i + 5]; s6 = esrc[i + 6]; s7 = esrc[i + 7];    \
      }                                                                            \
      ACC8(u0) ACC8(u1) ACC8(u2) ACC8(u3) ACC8(u4) ACC8(u5) ACC8(u6) ACC8(u7)      \
    }                                                                              \
  }                                                                                \
  if (i + 4 <= e) {                                                                \
    int s0 = esrc[i], s1 = esrc[i + 1], s2 = esrc[i + 2], s3 = esrc[i + 3];        \
    uint4 u0 = *(const uint4*)(fb + (size_t)s0 * 64);                              \
    uint4 u1 = *(const uint4*)(fb + (size_t)s1 * 64);                              \
    uint4 u2 = *(const uint4*)(fb + (size_t)s2 * 64);                              \
    uint4 u3 = *(const uint4*)(fb + (size_t)s3 * 64);                              \
    ACC8(u0) ACC8(u1) ACC8(u2) ACC8(u3)                                            \
    i += 4;                                                                        \
  }                                                                                \
  if (i + 2 <= e) {                                                                \
    int s0 = esrc[i], s1 = esrc[i + 1];                                            \
    uint4 u0 = *(const uint4*)(fb + (size_t)s0 * 64);                              \
    uint4 u1 = *(const uint4*)(fb + (size_t)s1 * 64);                              \
    ACC8(u0) ACC8(u1)                                                              \
    i += 2;                                                                        \
  }                                                                                \
  if (i < e) {                                                                     \
    int s0 = esrc[i];                                                              \
    uint4 u0 = *(const uint4*)(fb + (size_t)s0 * 64);                              \
    ACC8(u0)                                                                       \
  }

// ---------------- fused: gather(agg1) -> LDS -> MFMA layer1+2 ----------------
__global__ __launch_bounds__(256) void kfusedG(const ushort* __restrict__ xb,
                                               const int* __restrict__ starts,
                                               const int* __restrict__ esrc,
                                               const ushort* __restrict__ WF,
                                               const float* __restrict__ b1,
                                               ushort* __restrict__ y,
                                               ushort* __restrict__ r2b) {
  __shared__ __align__(16) char hT[32768];   // 4 waves x 2 tiles x 4KB
  __shared__ __align__(16) char aggL[16384]; // 128 nodes x 64ch bf16, XOR swizzled
  int t = threadIdx.x, l = t & 63, wv = t >> 6;
  int n0 = blockIdx.x * 128 + wv * 32;
  int row = l & 15;
  int kg = l >> 4;

  // phase 1: gather agg1 for the block's 128 nodes into aggL
  {
    int grp = t >> 3;   // 0..31
    int lg = t & 7;
#pragma unroll
    for (int pass = 0; pass < 4; ++pass) {
      int nl = pass * 32 + grp;
      int w = blockIdx.x * 128 + nl;
      float a0 = 0.f, a1 = 0.f, a2 = 0.f, a3 = 0.f,
            a4 = 0.f, a5 = 0.f, a6 = 0.f, a7 = 0.f;
      if (w < NN) {
        int b = starts[w], e = starts[w + 1];
        GATHER_CORE8(xb)
      }
      uint4 o;
      o.x = (uint32_t)f2bf(a0) | ((uint32_t)f2bf(a1) << 16);
      o.y = (uint32_t)f2bf(a2) | ((uint32_t)f2bf(a3) << 16);
      o.z = (uint32_t)f2bf(a4) | ((uint32_t)f2bf(a5) << 16);
      o.w = (uint32_t)f2bf(a6) | ((uint32_t)f2bf(a7) << 16);
      int off = nl * 128 + lg * 16;
      off ^= (nl & 7) << 4;
      *(uint4*)(aggL + off) = o;
    }
  }
  __syncthreads();

  // phase 2: A-fragments — agg from LDS, x from global
  int nr0 = n0 + row;      if (nr0 > NN - 1) nr0 = NN - 1;
  int nr1 = n0 + 16 + row; if (nr1 > NN - 1) nr1 = NN - 1;
  int nl0 = wv * 32 + row, nl1 = nl0 + 16;

  short8 aA0[2], aX0[2], aA1[2], aX1[2];
  {
#pragma unroll
    for (int s = 0; s < 2; ++s) {
      int off0 = nl0 * 128 + s * 64 + kg * 16; off0 ^= (nl0 & 7) << 4;
      int off1 = nl1 * 128 + s * 64 + kg * 16; off1 ^= (nl1 & 7) << 4;
      aA0[s] = *(const short8*)(aggL + off0);
      aA1[s] = *(const short8*)(aggL + off1);
    }
    const ushort* xp0 = xb + (size_t)nr0 * 64 + kg * 8;
    aX0[0] = *(const short8*)(xp0);
    aX0[1] = *(const short8*)(xp0 + 32);
    const ushort* xp1 = xb + (size_t)nr1 * 64 + kg * 8;
    aX1[0] = *(const short8*)(xp1);
    aX1[1] = *(const short8*)(xp1 + 32);
  }

  const ushort* wf1rel = WF;
  const ushort* wf1root = WF + 8192;
  char* base0 = hT + wv * 8192;
  char* base1 = base0 + 4096;

#pragma unroll
  for (int tt = 0; tt < 8; ++tt) {
    f32x4 acc0 = {0.f, 0.f, 0.f, 0.f};
    f32x4 acc1 = {0.f, 0.f, 0.f, 0.f};
#pragma unroll
    for (int s = 0; s < 2; ++s) {
      short8 br = *(const short8*)(wf1rel + ((size_t)(tt * 2 + s) * 64 + l) * 8);
      short8 bo = *(const short8*)(wf1root + ((size_t)(tt * 2 + s) * 64 + l) * 8);
      acc0 = __builtin_amdgcn_mfma_f32_16x16x32_bf16(aA0[s], br, acc0, 0, 0, 0);
      acc0 = __builtin_amdgcn_mfma_f32_16x16x32_bf16(aX0[s], bo, acc0, 0, 0, 0);
      acc1 = __builtin_amdgcn_mfma_f32_16x16x32_bf16(aA1[s], br, acc1, 0, 0, 0);
      acc1 = __builtin_amdgcn_mfma_f32_16x16x32_bf16(aX1[s], bo, acc1, 0, 0, 0);
    }
    float bias = b1[tt * 16 + row];
#pragma unroll
    for (int r = 0; r < 4; ++r) {
      int nl = kg * 4 + r;
      int off = nl * 256 + (tt * 16 + row) * 2;
      off ^= (nl & 7) << 4;
      *(ushort*)(base0 + off) = f2bf(fmaxf(acc0[r] + bias, 0.f));
      *(ushort*)(base1 + off) = f2bf(fmaxf(acc1[r] + bias, 0.f));
    }
  }
  __syncthreads();

  short8 aH0[4], aH1[4];
#pragma unroll
  for (int s = 0; s < 4; ++s) {
    int off = row * 256 + s * 64 + kg * 16;
    off ^= (row & 7) << 4;
    aH0[s] = *(const short8*)(base0 + off);
    aH1[s] = *(const short8*)(base1 + off);
  }

  const ushort* wf2rel = WF + 16384;
  const ushort* wf2root = WF + 24576;
#pragma unroll
  for (int tt = 0; tt < 4; ++tt) {
    f32x4 accY0 = {0.f, 0.f, 0.f, 0.f};
    f32x4 accR0 = {0.f, 0.f, 0.f, 0.f};
    f32x4 accY1 = {0.f, 0.f, 0.f, 0.f};
    f32x4 accR1 = {0.f, 0.f, 0.f, 0.f};
#pragma unroll
    for (int s = 0; s < 4; ++s) {
      short8 br = *(const short8*)(wf2rel + ((size_t)(tt * 4 + s) * 64 + l) * 8);
      short8 bo = *(const short8*)(wf2root + ((size_t)(tt * 4 + s) * 64 + l) * 8);
      accY0 = __builtin_amdgcn_mfma_f32_16x16x32_bf16(aH0[s], br, accY0, 0, 0, 0);
      accR0 = __builtin_amdgcn_mfma_f32_16x16x32_bf16(aH0[s], bo, accR0, 0, 0, 0);
      accY1 = __builtin_amdgcn_mfma_f32_16x16x32_bf16(aH1[s], br, accY1, 0, 0, 0);
      accR1 = __builtin_amdgcn_mfma_f32_16x16x32_bf16(aH1[s], bo, accR1, 0, 0, 0);
    }
#pragma unroll
    for (int r = 0; r < 4; ++r) {
      int nd0 = n0 + kg * 4 + r;
      int nd1 = nd0 + 16;
      if (nd0 < NN) {
        y[(size_t)nd0 * 64 + tt * 16 + row] = f2bf(accY0[r]);
        r2b[(size_t)nd0 * 64 + tt * 16 + row] = f2bf(accR0[r]);
      }
      if (nd1 < NN) {
        y[(size_t)nd1 * 64 + tt * 16 + row] = f2bf(accY1[r]);
        r2b[(size_t)nd1 * 64 + tt * 16 + row] = f2bf(accR1[r]);
      }
    }
  }
}

// ---------------- gather(y) + h2 = relu(agg + r2b + b2) -> h2b ----------------
__global__ __launch_bounds__(256) void kgh2Q(const ushort* __restrict__ featb,
                                             const int* __restrict__ starts,
                                             const int* __restrict__ esrc,
                                             const ushort* __restrict__ r2b,
                                             const float* __restrict__ b2v,
                                             ushort* __restrict__ h2b) {
  int w = (blockIdx.x * 256 + threadIdx.x) >> 3;
  if (w >= NN) return;
  int lg = threadIdx.x & 7;
  int b = starts[w], e = starts[w + 1];
  float a0 = 0.f, a1 = 0.f, a2 = 0.f, a3 = 0.f,
        a4 = 0.f, a5 = 0.f, a6 = 0.f, a7 = 0.f;
  GATHER_CORE8(featb)
  uint4 ru = *(const uint4*)(r2b + (size_t)w * 64 + 8 * lg);
  float4 bA = *(const float4*)(b2v + 8 * lg);
  float4 bB = *(const float4*)(b2v + 8 * lg + 4);
  float v0 = fmaxf(a0 + bf2f((ushort)ru.x) + bA.x, 0.f);
  float v1 = fmaxf(a1 + bf2f((ushort)(ru.x >> 16)) + bA.y, 0.f);
  float v2 = fmaxf(a2 + bf2f((ushort)ru.y) + bA.z, 0.f);
  float v3 = fmaxf(a3 + bf2f((ushort)(ru.y >> 16)) + bA.w, 0.f);
  float v4 = fmaxf(a4 + bf2f((ushort)ru.z) + bB.x, 0.f);
  float v5 = fmaxf(a5 + bf2f((ushort)(ru.z >> 16)) + bB.y, 0.f);
  float v6 = fmaxf(a6 + bf2f((ushort)ru.w) + bB.z, 0.f);
  float v7 = fmaxf(a7 + bf2f((ushort)(ru.w >> 16)) + bB.w, 0.f);
  uint4 o;
  o.x = (uint32_t)f2bf(v0) | ((uint32_t)f2bf(v1) << 16);
  o.y = (uint32_t)f2bf(v2) | ((uint32_t)f2bf(v3) << 16);
  o.z = (uint32_t)f2bf(v4) | ((uint32_t)f2bf(v5) << 16);
  o.w = (uint32_t)f2bf(v6) | ((uint32_t)f2bf(v7) << 16);
  *(uint4*)(h2b + (size_t)w * 64 + 8 * lg) = o;
}

// ---------------- parallel partial pooling: 24 slices/graph, atomic-free ----------------
__global__ __launch_bounds__(256) void kpoolpart(const ushort* __restrict__ h2b,
                                                 const int* __restrict__ batch,
                                                 float* __restrict__ poolP) {
  __shared__ int gbs[2];
  __shared__ float part[4][64];
  int g = blockIdx.x / PSLICE, sl = blockIdx.x % PSLICE;
  int t = threadIdx.x;
  if (t < 2) {
    int target = g + t;
    int lo = 0, hi = NN;
    while (lo < hi) { int m = (lo + hi) >> 1; if (batch[m] < target) lo = m + 1; else hi = m; }
    gbs[t] = lo;
  }
  __syncthreads();
  int n0 = gbs[0], len = gbs[1] - n0;
  int lo = n0 + (int)((long)len * sl / PSLICE);
  int hi = n0 + (int)((long)len * (sl + 1) / PSLICE);
  int ch = t & 63, sub = t >> 6;
  float acc = 0.f;
  int n = lo + sub;
  for (; n + 12 < hi; n += 16) {
    float v0 = bf2f(h2b[(size_t)n * 64 + ch]);
    float v1 = bf2f(h2b[(size_t)(n + 4) * 64 + ch]);
    float v2 = bf2f(h2b[(size_t)(n + 8) * 64 + ch]);
    float v3 = bf2f(h2b[(size_t)(n + 12) * 64 + ch]);
    acc += (v0 + v1) + (v2 + v3);
  }
  for (; n < hi; n += 4) acc += bf2f(h2b[(size_t)n * 64 + ch]);
  part[sub][ch] = acc;
  __syncthreads();
  if (t < 64)
    poolP[(size_t)blockIdx.x * 64 + t] = part[0][t] + part[1][t] + part[2][t] + part[3][t];
}

// ---------------- final: sum 24 partials, divide, MLPs ----------------
__global__ __launch_bounds__(64) void kfinal3(
    const float* __restrict__ poolP, const int* __restrict__ batch,
    const float* __restrict__ es_w1, const float* __restrict__ es_b1,
    const float* __restrict__ es_w2, const float* __restrict__ es_b2,
    const float* __restrict__ es_w3, const float* __restrict__ es_b3,
    const float* __restrict__ d_w1, const float* __restrict__ d_b1,
    const float* __restrict__ d_w2, const float* __restrict__ d_b2,
    const float* __restrict__ d_w3, const float* __restrict__ d_b3,
    float* __restrict__ out) {
  __shared__ float h3[64];
  __shared__ float z1s[8];
  __shared__ float t2s[8];
  __shared__ int gbs[2];
  int g = blockIdx.x;
  int l = threadIdx.x;
  if (l < 2) {
    int target = g + l;
    int lo = 0, hi = NN;
    while (lo < hi) { int m = (lo + hi) >> 1; if (batch[m] < target) lo = m + 1; else hi = m; }
    gbs[l] = lo;
  }
  float s = 0.f;
#pragma unroll
  for (int k = 0; k < PSLICE; ++k) s += poolP[(size_t)(g * PSLICE + k) * 64 + l];
  __syncthreads();
  float c = fmaxf((float)(gbs[1] - gbs[0]), 1.f);
  float h = s / c;
  h3[l] = h;
  out[g * 64 + l] = h;
  __syncthreads();
  if (l < 8) {
    float a = es_b1[l];
#pragma unroll
    for (int k = 0; k < 64; ++k) a += es_w1[l * 64 + k] * h3[k];
    z1s[l] = fmaxf(a, 0.f);
  }
  __syncthreads();
  if (l == 0) {
    float z2[4];
#pragma unroll
    for (int j = 0; j < 4; ++j) {
      float a = es_b2[j];
#pragma unroll
      for (int k = 0; k < 8; ++k) a += es_w2[j * 8 + k] * z1s[k];
      z2[j] = fmaxf(a, 0.f);
    }
    float z = es_b3[0];
#pragma unroll
    for (int k = 0; k < 4; ++k) z += es_w3[k] * z2[k];
    float t1[4];
#pragma unroll
    for (int j = 0; j < 4; ++j) t1[j] = fmaxf(d_w1[j] * z + d_b1[j], 0.f);
#pragma unroll
    for (int j = 0; j < 8; ++j) {
      float a = d_b2[j];
#pragma unroll
      for (int k = 0; k < 4; ++k) a += d_w2[j * 4 + k] * t1[k];
      t2s[j] = fmaxf(a, 0.f);
    }
  }
  __syncthreads();
  float a = d_b3[l];
#pragma unroll
  for (int k = 0; k < 8; ++k) a += d_w3[l * 8 + k] * t2s[k];
  out[4096 + g * 64 + l] = a;
}

extern "C" void kernel_launch(void* const* d_in, const int* in_sizes, int n_in,
                              void* d_out, int out_size, void* d_ws, size_t ws_size,
                              hipStream_t stream) {
  const float* x = (const float*)d_in[0];
  const int* ei = (const int*)d_in[1];
  const int* srcI = ei;
  const int* dstI = ei + EE;
  const int* batch = (const int*)d_in[2];
  const float* w1_rel = (const float*)d_in[3];
  const float* b1_rel = (const float*)d_in[4];
  const float* w1_root = (const float*)d_in[5];
  const float* w2_rel = (const float*)d_in[6];
  const float* b2_rel = (const float*)d_in[7];
  const float* w2_root = (const float*)d_in[8];
  const float* es_w1 = (const float*)d_in[9];
  const float* es_b1 = (const float*)d_in[10];
  const float* es_w2 = (const float*)d_in[11];
  const float* es_b2 = (const float*)d_in[12];
  const float* es_w3 = (const float*)d_in[13];
  const float* es_b3 = (const float*)d_in[14];
  const float* d_w1 = (const float*)d_in[15];
  const float* d_b1 = (const float*)d_in[16];
  const float* d_w2 = (const float*)d_in[17];
  const float* d_b2 = (const float*)d_in[18];
  const float* d_w3 = (const float*)d_in[19];
  const float* d_b3 = (const float*)d_in[20];

  ushort* xb = (ushort*)d_ws;                     // NN*64 bf16
  ushort* yb = xb + (size_t)NN * 64;              // NN*64 bf16
  ushort* r2b = yb + (size_t)NN * 64;             // NN*64 bf16
  ushort* h2b = r2b + (size_t)NN * 64;            // NN*64 bf16
  ushort* WF = h2b + (size_t)NN * 64;             // 32768 bf16
  float* poolP = (float*)(WF + 32768);            // 64*PSLICE*64 f32
  int* starts = (int*)(poolP + 64 * PSLICE * 64); // NN+1
  int* histG = starts + NN + 1;                   // NCHUNK*NBUCK
  int* relG = histG + NCHUNK * NBUCK;             // NCHUNK*NBUCK
  int* bucketTotal = relG + NCHUNK * NBUCK;       // NBUCK
  uint32_t* pairsG = (uint32_t*)(bucketTotal + NBUCK);  // EE
  int* esrc = (int*)(pairsG + EE);                // EE
  float* out = (float*)d_out;

  kfront<<<32 + XB_NB + NCHUNK, 256, 0, stream>>>(w1_rel, w1_root, w2_rel, w2_root,
                                                  x, dstI, WF, xb, histG);
  kscan2d<<<NBUCK, 512, 0, stream>>>(histG, relG, bucketTotal);
  kbinA2<<<NCHUNK, 256, 0, stream>>>(srcI, dstI, histG, relG, bucketTotal, pairsG);
  kbinB<<<NBUCK, 256, 0, stream>>>(pairsG, bucketTotal, starts, esrc);
  kfusedG<<<(NN + 127) / 128, 256, 0, stream>>>(xb, starts, esrc, WF, b1_rel, yb, r2b);
  kgh2Q<<<(NN * 8 + 255) / 256, 256, 0, stream>>>(yb, starts, esrc, r2b, b2_rel, h2b);
  kpoolpart<<<64 * PSLICE, 256, 0, stream>>>(h2b, batch, poolP);
  kfinal3<<<64, 64, 0, stream>>>(poolP, batch, es_w1, es_b1, es_w2, es_b2, es_w3, es_b3,
                                 d_w1, d_b1, d_w2, d_b2, d_w3, d_b3, out);
}

// Round 16
// 134.999 us; speedup vs baseline: 1.0758x; 1.0758x over previous
//
#include <hip/hip_runtime.h>
#include <stdint.h>

#define NN 100000
#define EE 1250000
#define NBUCK 196          // ceil(NN/512)
#define CHUNK 4096
#define NCHUNK ((EE + CHUNK - 1) / CHUNK)  // 306
#define PSLICE 24          // pooling slices per graph
#define XB_NB ((NN * 64 / 4 + 255) / 256)  // 6250

typedef __attribute__((ext_vector_type(8))) short short8;
typedef __attribute__((ext_vector_type(4))) float f32x4;

__device__ inline ushort f2bf(float f) {
  union { float f; uint32_t u; } v; v.f = f;
  uint32_t r = v.u + 0x7FFF + ((v.u >> 16) & 1);
  return (ushort)(r >> 16);
}
__device__ inline float bf2f(ushort h) {
  union { uint32_t u; float f; } v; v.u = ((uint32_t)h) << 16;
  return v.f;
}

// ---------------- merged front: weight frags | x->bf16 | per-chunk histogram ----------
__global__ __launch_bounds__(256) void kfront(const float* __restrict__ w1_rel,
                                              const float* __restrict__ w1_root,
                                              const float* __restrict__ w2_rel,
                                              const float* __restrict__ w2_root,
                                              const float* __restrict__ x,
                                              const int* __restrict__ dstI,
                                              ushort* __restrict__ WF,
                                              ushort* __restrict__ xb,
                                              int* __restrict__ histG) {
  __shared__ int h[NBUCK];
  int t = threadIdx.x;
  int blk = blockIdx.x;
  if (blk < 32) {
    int idx = blk * 256 + t;
    if (idx < 8192) {
      int j = idx & 7, l = (idx >> 3) & 63, ts = idx >> 9;
      {
        int s = ts & 1, tt = ts >> 1;
        int o = tt * 16 + (l & 15), k = s * 32 + (l >> 4) * 8 + j;
        WF[idx] = f2bf(w1_rel[o * 64 + k]);
        WF[8192 + idx] = f2bf(w1_root[o * 64 + k]);
      }
      {
        int s = ts & 3, tt = ts >> 2;
        int o = tt * 16 + (l & 15), k = s * 32 + (l >> 4) * 8 + j;
        WF[16384 + idx] = f2bf(w2_rel[o * 128 + k]);
        WF[24576 + idx] = f2bf(w2_root[o * 128 + k]);
      }
    }
  } else if (blk < 32 + XB_NB) {
    int i = ((blk - 32) * 256 + t) * 4;
    if (i < NN * 64) {
      float4 v = *reinterpret_cast<const float4*>(x + i);
      ushort o[4] = {f2bf(v.x), f2bf(v.y), f2bf(v.z), f2bf(v.w)};
      *reinterpret_cast<uint2*>(xb + i) = *reinterpret_cast<uint2*>(o);
    }
  } else {
    int c = blk - 32 - XB_NB;  // chunk id
    if (t < NBUCK) h[t] = 0;
    __syncthreads();
    int cb = c * CHUNK;
    int cc = EE - cb; if (cc > CHUNK) cc = CHUNK;
    for (int i = t; i < cc; i += 256) atomicAdd(&h[dstI[cb + i] >> 9], 1);
    __syncthreads();
    if (t < NBUCK) histG[c * NBUCK + t] = h[t];
  }
}

// ---------------- 2D scan: for each bucket, exclusive scan over chunks ----------------
__global__ __launch_bounds__(512) void kscan2d(const int* __restrict__ histG,
                                               int* __restrict__ relG,
                                               int* __restrict__ bucketTotal) {
  __shared__ int sm[512];
  int b = blockIdx.x;
  int t = threadIdx.x;
  int v = (t < NCHUNK) ? histG[t * NBUCK + b] : 0;
  sm[t] = v;
  __syncthreads();
  for (int d = 1; d < 512; d <<= 1) {
    int u = (t >= d) ? sm[t - d] : 0;
    __syncthreads();
    sm[t] += u;
    __syncthreads();
  }
  if (t < NCHUNK) relG[t * NBUCK + b] = sm[t] - v;
  if (t == 511) bucketTotal[b] = sm[511];
}

// ---------------- binning pass 2: local bucketStart scan + LDS reorder + run copy ----
__global__ __launch_bounds__(256) void kbinA2(const int* __restrict__ srcI,
                                              const int* __restrict__ dstI,
                                              const int* __restrict__ histG,
                                              const int* __restrict__ relG,
                                              const int* __restrict__ bucketTotal,
                                              uint32_t* __restrict__ pairsG) {
  __shared__ uint32_t pko[CHUNK];       // 16 KB
  __shared__ int ss[256];
  __shared__ int bsL[NBUCK];
  __shared__ int ex[NBUCK + 1];
  __shared__ int cur[NBUCK];
  __shared__ int gb[NBUCK];
  int t = threadIdx.x;
  int cb = blockIdx.x * CHUNK;
  int cc = EE - cb; if (cc > CHUNK) cc = CHUNK;

  {
    int bv = (t < NBUCK) ? bucketTotal[t] : 0;
    ss[t] = bv;
    __syncthreads();
    for (int d = 1; d < 256; d <<= 1) {
      int u = (t >= d) ? ss[t - d] : 0;
      __syncthreads();
      ss[t] += u;
      __syncthreads();
    }
    if (t < NBUCK) bsL[t] = ss[t] - bv;
    __syncthreads();
  }
  int v = (t < NBUCK) ? histG[blockIdx.x * NBUCK + t] : 0;
  ss[t] = v;
  __syncthreads();
  for (int d = 1; d < 256; d <<= 1) {
    int u = (t >= d) ? ss[t - d] : 0;
    __syncthreads();
    ss[t] += u;
    __syncthreads();
  }
  if (t < NBUCK) {
    ex[t] = ss[t] - v;
    cur[t] = ss[t] - v;
    gb[t] = bsL[t] + relG[blockIdx.x * NBUCK + t];
  }
  if (t == NBUCK - 1) ex[NBUCK] = ss[t];
  __syncthreads();
  for (int i = t; i < cc; i += 256) {
    int d = dstI[cb + i];
    int s = srcI[cb + i];
    int b = d >> 9;
    int p = atomicAdd(&cur[b], 1);
    pko[p] = (uint32_t)s | ((uint32_t)(d & 511) << 17);
  }
  __syncthreads();
  if (t < NBUCK) {
    int base = ex[t], cnt = ex[t + 1] - base, g0 = gb[t];
    for (int j = 0; j < cnt; ++j) pairsG[g0 + j] = pko[base + j];
  }
}

// ---------------- pass B: per-bucket node-level CSR (starts + esrc) ----------------
__global__ __launch_bounds__(256) void kbinB(const uint32_t* __restrict__ pairsG,
                                             const int* __restrict__ bucketTotal,
                                             int* __restrict__ starts,
                                             int* __restrict__ esrc) {
  __shared__ int hist[512];
  __shared__ int ex2[512];
  __shared__ int part[256];
  __shared__ int baseS;
  int t = threadIdx.x;
  int b = blockIdx.x;
  int nbase = b << 9;
  {
    int bv = (t < NBUCK) ? bucketTotal[t] : 0;
    part[t] = bv;
    __syncthreads();
    for (int d = 1; d < 256; d <<= 1) {
      int u = (t >= d) ? part[t - d] : 0;
      __syncthreads();
      part[t] += u;
      __syncthreads();
    }
    if (t == b) baseS = part[t] - bv;
    __syncthreads();
  }
  int base = baseS;
  int ecnt = bucketTotal[b];

  hist[t] = 0; hist[t + 256] = 0;
  __syncthreads();
  for (int i = t; i < ecnt; i += 256) atomicAdd(&hist[pairsG[base + i] >> 17], 1);
  __syncthreads();
  int a = hist[2 * t], c = hist[2 * t + 1];
  part[t] = a + c;
  __syncthreads();
  for (int d = 1; d < 256; d <<= 1) {
    int u = (t >= d) ? part[t - d] : 0;
    __syncthreads();
    part[t] += u;
    __syncthreads();
  }
  int pex = part[t] - (a + c);
  ex2[2 * t] = pex;
  ex2[2 * t + 1] = pex + a;
  __syncthreads();
  for (int n = t; n < 512; n += 256) {
    int node = nbase + n;
    if (node < NN) starts[node] = base + ex2[n];
  }
  if (b == NBUCK - 1 && t == 0) starts[NN] = EE;
  for (int n = t; n < 512; n += 256) hist[n] = ex2[n];
  __syncthreads();
  for (int i = t; i < ecnt; i += 256) {
    uint32_t p = pairsG[base + i];
    int dl = p >> 17;
    int s = p & 0x1FFFF;
    int lp = atomicAdd(&hist[dl], 1);
    esrc[base + lp] = s;
  }
}

// ---------------- 8-lane-per-node gather core: 16B loads, 8-deep pipeline ----------------
#define ACC8(u)                                                                    \
  a0 += bf2f((ushort)(u).x); a1 += bf2f((ushort)((u).x >> 16));                    \
  a2 += bf2f((ushort)(u).y); a3 += bf2f((ushort)((u).y >> 16));                    \
  a4 += bf2f((ushort)(u).z); a5 += bf2f((ushort)((u).z >> 16));                    \
  a6 += bf2f((ushort)(u).w); a7 += bf2f((ushort)((u).w >> 16));

#define GATHER_CORE8(featb)                                                        \
  float a0 = 0.f, a1 = 0.f, a2 = 0.f, a3 = 0.f,                                    \
        a4 = 0.f, a5 = 0.f, a6 = 0.f, a7 = 0.f;                                    \
  const ushort* fb = (featb) + 8 * lg;                                             \
  int i = b;                                                                       \
  {                                                                                \
    int s0 = 0, s1 = 0, s2 = 0, s3 = 0, s4 = 0, s5 = 0, s6 = 0, s7 = 0;            \
    bool have = (i + 8 <= e);                                                      \
    if (have) {                                                                    \
      s0 = esrc[i];     s1 = esrc[i + 1]; s2 = esrc[i + 2]; s3 = esrc[i + 3];      \
      s4 = esrc[i + 4]; s5 = esrc[i + 5]; s6 = esrc[i + 6]; s7 = esrc[i + 7];      \
    }                                                                              \
    while (have) {                                                                 \
      uint4 u0 = *(const uint4*)(fb + (size_t)s0 * 64);                            \
      uint4 u1 = *(const uint4*)(fb + (size_t)s1 * 64);                            \
      uint4 u2 = *(const uint4*)(fb + (size_t)s2 * 64);                            \
      uint4 u3 = *(const uint4*)(fb + (size_t)s3 * 64);                            \
      uint4 u4 = *(const uint4*)(fb + (size_t)s4 * 64);                            \
      uint4 u5 = *(const uint4*)(fb + (size_t)s5 * 64);                            \
      uint4 u6 = *(const uint4*)(fb + (size_t)s6 * 64);                            \
      uint4 u7 = *(const uint4*)(fb + (size_t)s7 * 64);                            \
      i += 8;                                                                      \
      have = (i + 8 <= e);                                                         \
      if (have) {                                                                  \
        s0 = esrc[i];     s1 = esrc[i + 1]; s2 = esrc[i + 2]; s3 = esrc[i + 3];    \
        s4 = esrc[i + 4]; s5 = esrc[i + 5]; s6 = esrc[i + 6]; s7 = esrc[i + 7];    \
      }                                                                            \
      ACC8(u0) ACC8(u1) ACC8(u2) ACC8(u3) ACC8(u4) ACC8(u5) ACC8(u6) ACC8(u7)      \
    }                                                                              \
  }                                                                                \
  if (i + 4 <= e) {                                                                \
    int s0 = esrc[i], s1 = esrc[i + 1], s2 = esrc[i + 2], s3 = esrc[i + 3];        \
    uint4 u0 = *(const uint4*)(fb + (size_t)s0 * 64);                              \
    uint4 u1 = *(const uint4*)(fb + (size_t)s1 * 64);                              \
    uint4 u2 = *(const uint4*)(fb + (size_t)s2 * 64);                              \
    uint4 u3 = *(const uint4*)(fb + (size_t)s3 * 64);                              \
    ACC8(u0) ACC8(u1) ACC8(u2) ACC8(u3)                                            \
    i += 4;                                                                        \
  }                                                                                \
  if (i + 2 <= e) {                                                                \
    int s0 = esrc[i], s1 = esrc[i + 1];                                            \
    uint4 u0 = *(const uint4*)(fb + (size_t)s0 * 64);                              \
    uint4 u1 = *(const uint4*)(fb + (size_t)s1 * 64);                              \
    ACC8(u0) ACC8(u1)                                                              \
    i += 2;                                                                        \
  }                                                                                \
  if (i < e) {                                                                     \
    int s0 = esrc[i];                                                              \
    uint4 u0 = *(const uint4*)(fb + (size_t)s0 * 64);                              \
    ACC8(u0)                                                                       \
  }

__global__ __launch_bounds__(256) void kgatherQ(const ushort* __restrict__ featb,
                                                const int* __restrict__ starts,
                                                const int* __restrict__ esrc,
                                                ushort* __restrict__ outb) {
  int w = (blockIdx.x * 256 + threadIdx.x) >> 3;
  if (w >= NN) return;
  int lg = threadIdx.x & 7;
  int b = starts[w], e = starts[w + 1];
  GATHER_CORE8(featb)
  uint4 o;
  o.x = (uint32_t)f2bf(a0) | ((uint32_t)f2bf(a1) << 16);
  o.y = (uint32_t)f2bf(a2) | ((uint32_t)f2bf(a3) << 16);
  o.z = (uint32_t)f2bf(a4) | ((uint32_t)f2bf(a5) << 16);
  o.w = (uint32_t)f2bf(a6) | ((uint32_t)f2bf(a7) << 16);
  *(uint4*)(outb + (size_t)w * 64 + 8 * lg) = o;
}

__global__ __launch_bounds__(256) void kgh2Q(const ushort* __restrict__ featb,
                                             const int* __restrict__ starts,
                                             const int* __restrict__ esrc,
                                             const ushort* __restrict__ r2b,
                                             const float* __restrict__ b2v,
                                             ushort* __restrict__ h2b) {
  int w = (blockIdx.x * 256 + threadIdx.x) >> 3;
  if (w >= NN) return;
  int lg = threadIdx.x & 7;
  int b = starts[w], e = starts[w + 1];
  GATHER_CORE8(featb)
  uint4 ru = *(const uint4*)(r2b + (size_t)w * 64 + 8 * lg);
  float4 bA = *(const float4*)(b2v + 8 * lg);
  float4 bB = *(const float4*)(b2v + 8 * lg + 4);
  float v0 = fmaxf(a0 + bf2f((ushort)ru.x) + bA.x, 0.f);
  float v1 = fmaxf(a1 + bf2f((ushort)(ru.x >> 16)) + bA.y, 0.f);
  float v2 = fmaxf(a2 + bf2f((ushort)ru.y) + bA.z, 0.f);
  float v3 = fmaxf(a3 + bf2f((ushort)(ru.y >> 16)) + bA.w, 0.f);
  float v4 = fmaxf(a4 + bf2f((ushort)ru.z) + bB.x, 0.f);
  float v5 = fmaxf(a5 + bf2f((ushort)(ru.z >> 16)) + bB.y, 0.f);
  float v6 = fmaxf(a6 + bf2f((ushort)ru.w) + bB.z, 0.f);
  float v7 = fmaxf(a7 + bf2f((ushort)(ru.w >> 16)) + bB.w, 0.f);
  uint4 o;
  o.x = (uint32_t)f2bf(v0) | ((uint32_t)f2bf(v1) << 16);
  o.y = (uint32_t)f2bf(v2) | ((uint32_t)f2bf(v3) << 16);
  o.z = (uint32_t)f2bf(v4) | ((uint32_t)f2bf(v5) << 16);
  o.w = (uint32_t)f2bf(v6) | ((uint32_t)f2bf(v7) << 16);
  *(uint4*)(h2b + (size_t)w * 64 + 8 * lg) = o;
}

// ---------------- fused MFMA, 2 M-tiles/wave (weight-fragment reuse) ----------------
__global__ __launch_bounds__(256) void kfused(const ushort* __restrict__ xb,
                                              const ushort* __restrict__ aggb,
                                              const ushort* __restrict__ WF,
                                              const float* __restrict__ b1,
                                              ushort* __restrict__ y,
                                              ushort* __restrict__ r2b) {
  __shared__ __align__(16) char hT[32768];  // 4 waves x 2 tiles x 4KB
  int t = threadIdx.x, l = t & 63, wv = t >> 6;
  int n0 = blockIdx.x * 128 + wv * 32;
  int row = l & 15;
  int kg = l >> 4;
  int nr0 = n0 + row;      if (nr0 > NN - 1) nr0 = NN - 1;
  int nr1 = n0 + 16 + row; if (nr1 > NN - 1) nr1 = NN - 1;

  short8 aA0[2], aX0[2], aA1[2], aX1[2];
  {
    const ushort* ap0 = aggb + (size_t)nr0 * 64 + kg * 8;
    aA0[0] = *(const short8*)(ap0);
    aA0[1] = *(const short8*)(ap0 + 32);
    const ushort* xp0 = xb + (size_t)nr0 * 64 + kg * 8;
    aX0[0] = *(const short8*)(xp0);
    aX0[1] = *(const short8*)(xp0 + 32);
    const ushort* ap1 = aggb + (size_t)nr1 * 64 + kg * 8;
    aA1[0] = *(const short8*)(ap1);
    aA1[1] = *(const short8*)(ap1 + 32);
    const ushort* xp1 = xb + (size_t)nr1 * 64 + kg * 8;
    aX1[0] = *(const short8*)(xp1);
    aX1[1] = *(const short8*)(xp1 + 32);
  }

  const ushort* wf1rel = WF;
  const ushort* wf1root = WF + 8192;
  char* base0 = hT + wv * 8192;
  char* base1 = base0 + 4096;

#pragma unroll
  for (int tt = 0; tt < 8; ++tt) {
    f32x4 acc0 = {0.f, 0.f, 0.f, 0.f};
    f32x4 acc1 = {0.f, 0.f, 0.f, 0.f};
#pragma unroll
    for (int s = 0; s < 2; ++s) {
      short8 br = *(const short8*)(wf1rel + ((size_t)(tt * 2 + s) * 64 + l) * 8);
      short8 bo = *(const short8*)(wf1root + ((size_t)(tt * 2 + s) * 64 + l) * 8);
      acc0 = __builtin_amdgcn_mfma_f32_16x16x32_bf16(aA0[s], br, acc0, 0, 0, 0);
      acc0 = __builtin_amdgcn_mfma_f32_16x16x32_bf16(aX0[s], bo, acc0, 0, 0, 0);
      acc1 = __builtin_amdgcn_mfma_f32_16x16x32_bf16(aA1[s], br, acc1, 0, 0, 0);
      acc1 = __builtin_amdgcn_mfma_f32_16x16x32_bf16(aX1[s], bo, acc1, 0, 0, 0);
    }
    float bias = b1[tt * 16 + row];
#pragma unroll
    for (int r = 0; r < 4; ++r) {
      int nl = kg * 4 + r;
      int off = nl * 256 + (tt * 16 + row) * 2;
      off ^= (nl & 7) << 4;
      *(ushort*)(base0 + off) = f2bf(fmaxf(acc0[r] + bias, 0.f));
      *(ushort*)(base1 + off) = f2bf(fmaxf(acc1[r] + bias, 0.f));
    }
  }
  __syncthreads();

  short8 aH0[4], aH1[4];
#pragma unroll
  for (int s = 0; s < 4; ++s) {
    int off = row * 256 + s * 64 + kg * 16;
    off ^= (row & 7) << 4;
    aH0[s] = *(const short8*)(base0 + off);
    aH1[s] = *(const short8*)(base1 + off);
  }

  const ushort* wf2rel = WF + 16384;
  const ushort* wf2root = WF + 24576;
#pragma unroll
  for (int tt = 0; tt < 4; ++tt) {
    f32x4 accY0 = {0.f, 0.f, 0.f, 0.f};
    f32x4 accR0 = {0.f, 0.f, 0.f, 0.f};
    f32x4 accY1 = {0.f, 0.f, 0.f, 0.f};
    f32x4 accR1 = {0.f, 0.f, 0.f, 0.f};
#pragma unroll
    for (int s = 0; s < 4; ++s) {
      short8 br = *(const short8*)(wf2rel + ((size_t)(tt * 4 + s) * 64 + l) * 8);
      short8 bo = *(const short8*)(wf2root + ((size_t)(tt * 4 + s) * 64 + l) * 8);
      accY0 = __builtin_amdgcn_mfma_f32_16x16x32_bf16(aH0[s], br, accY0, 0, 0, 0);
      accR0 = __builtin_amdgcn_mfma_f32_16x16x32_bf16(aH0[s], bo, accR0, 0, 0, 0);
      accY1 = __builtin_amdgcn_mfma_f32_16x16x32_bf16(aH1[s], br, accY1, 0, 0, 0);
      accR1 = __builtin_amdgcn_mfma_f32_16x16x32_bf16(aH1[s], bo, accR1, 0, 0, 0);
    }
#pragma unroll
    for (int r = 0; r < 4; ++r) {
      int nd0 = n0 + kg * 4 + r;
      int nd1 = nd0 + 16;
      if (nd0 < NN) {
        y[(size_t)nd0 * 64 + tt * 16 + row] = f2bf(accY0[r]);
        r2b[(size_t)nd0 * 64 + tt * 16 + row] = f2bf(accR0[r]);
      }
      if (nd1 < NN) {
        y[(size_t)nd1 * 64 + tt * 16 + row] = f2bf(accY1[r]);
        r2b[(size_t)nd1 * 64 + tt * 16 + row] = f2bf(accR1[r]);
      }
    }
  }
}

// ---------------- parallel partial pooling: 24 slices/graph, atomic-free ----------------
__global__ __launch_bounds__(256) void kpoolpart(const ushort* __restrict__ h2b,
                                                 const int* __restrict__ batch,
                                                 float* __restrict__ poolP) {
  __shared__ int gbs[2];
  __shared__ float part[4][64];
  int g = blockIdx.x / PSLICE, sl = blockIdx.x % PSLICE;
  int t = threadIdx.x;
  if (t < 2) {
    int target = g + t;
    int lo = 0, hi = NN;
    while (lo < hi) { int m = (lo + hi) >> 1; if (batch[m] < target) lo = m + 1; else hi = m; }
    gbs[t] = lo;
  }
  __syncthreads();
  int n0 = gbs[0], len = gbs[1] - n0;
  int lo = n0 + (int)((long)len * sl / PSLICE);
  int hi = n0 + (int)((long)len * (sl + 1) / PSLICE);
  int ch = t & 63, sub = t >> 6;
  float acc = 0.f;
  int n = lo + sub;
  for (; n + 12 < hi; n += 16) {
    float v0 = bf2f(h2b[(size_t)n * 64 + ch]);
    float v1 = bf2f(h2b[(size_t)(n + 4) * 64 + ch]);
    float v2 = bf2f(h2b[(size_t)(n + 8) * 64 + ch]);
    float v3 = bf2f(h2b[(size_t)(n + 12) * 64 + ch]);
    acc += (v0 + v1) + (v2 + v3);
  }
  for (; n < hi; n += 4) acc += bf2f(h2b[(size_t)n * 64 + ch]);
  part[sub][ch] = acc;
  __syncthreads();
  if (t < 64)
    poolP[(size_t)blockIdx.x * 64 + t] = part[0][t] + part[1][t] + part[2][t] + part[3][t];
}

// ---------------- final: sum 24 partials, divide, MLPs ----------------
__global__ __launch_bounds__(64) void kfinal3(
    const float* __restrict__ poolP, const int* __restrict__ batch,
    const float* __restrict__ es_w1, const float* __restrict__ es_b1,
    const float* __restrict__ es_w2, const float* __restrict__ es_b2,
    const float* __restrict__ es_w3, const float* __restrict__ es_b3,
    const float* __restrict__ d_w1, const float* __restrict__ d_b1,
    const float* __restrict__ d_w2, const float* __restrict__ d_b2,
    const float* __restrict__ d_w3, const float* __restrict__ d_b3,
    float* __restrict__ out) {
  __shared__ float h3[64];
  __shared__ float z1s[8];
  __shared__ float t2s[8];
  __shared__ int gbs[2];
  int g = blockIdx.x;
  int l = threadIdx.x;
  if (l < 2) {
    int target = g + l;
    int lo = 0, hi = NN;
    while (lo < hi) { int m = (lo + hi) >> 1; if (batch[m] < target) lo = m + 1; else hi = m; }
    gbs[l] = lo;
  }
  float s = 0.f;
#pragma unroll
  for (int k = 0; k < PSLICE; ++k) s += poolP[(size_t)(g * PSLICE + k) * 64 + l];
  __syncthreads();
  float c = fmaxf((float)(gbs[1] - gbs[0]), 1.f);
  float h = s / c;
  h3[l] = h;
  out[g * 64 + l] = h;
  __syncthreads();
  if (l < 8) {
    float a = es_b1[l];
#pragma unroll
    for (int k = 0; k < 64; ++k) a += es_w1[l * 64 + k] * h3[k];
    z1s[l] = fmaxf(a, 0.f);
  }
  __syncthreads();
  if (l == 0) {
    float z2[4];
#pragma unroll
    for (int j = 0; j < 4; ++j) {
      float a = es_b2[j];
#pragma unroll
      for (int k = 0; k < 8; ++k) a += es_w2[j * 8 + k] * z1s[k];
      z2[j] = fmaxf(a, 0.f);
    }
    float z = es_b3[0];
#pragma unroll
    for (int k = 0; k < 4; ++k) z += es_w3[k] * z2[k];
    float t1[4];
#pragma unroll
    for (int j = 0; j < 4; ++j) t1[j] = fmaxf(d_w1[j] * z + d_b1[j], 0.f);
#pragma unroll
    for (int j = 0; j < 8; ++j) {
      float a = d_b2[j];
#pragma unroll
      for (int k = 0; k < 4; ++k) a += d_w2[j * 4 + k] * t1[k];
      t2s[j] = fmaxf(a, 0.f);
    }
  }
  __syncthreads();
  float a = d_b3[l];
#pragma unroll
  for (int k = 0; k < 8; ++k) a += d_w3[l * 8 + k] * t2s[k];
  out[4096 + g * 64 + l] = a;
}

extern "C" void kernel_launch(void* const* d_in, const int* in_sizes, int n_in,
                              void* d_out, int out_size, void* d_ws, size_t ws_size,
                              hipStream_t stream) {
  const float* x = (const float*)d_in[0];
  const int* ei = (const int*)d_in[1];
  const int* srcI = ei;
  const int* dstI = ei + EE;
  const int* batch = (const int*)d_in[2];
  const float* w1_rel = (const float*)d_in[3];
  const float* b1_rel = (const float*)d_in[4];
  const float* w1_root = (const float*)d_in[5];
  const float* w2_rel = (const float*)d_in[6];
  const float* b2_rel = (const float*)d_in[7];
  const float* w2_root = (const float*)d_in[8];
  const float* es_w1 = (const float*)d_in[9];
  const float* es_b1 = (const float*)d_in[10];
  const float* es_w2 = (const float*)d_in[11];
  const float* es_b2 = (const float*)d_in[12];
  const float* es_w3 = (const float*)d_in[13];
  const float* es_b3 = (const float*)d_in[14];
  const float* d_w1 = (const float*)d_in[15];
  const float* d_b1 = (const float*)d_in[16];
  const float* d_w2 = (const float*)d_in[17];
  const float* d_b2 = (const float*)d_in[18];
  const float* d_w3 = (const float*)d_in[19];
  const float* d_b3 = (const float*)d_in[20];

  ushort* xb = (ushort*)d_ws;                     // NN*64 bf16
  ushort* aggb = xb + (size_t)NN * 64;            // NN*64 bf16
  ushort* yb = aggb + (size_t)NN * 64;            // NN*64 bf16
  ushort* r2b = yb + (size_t)NN * 64;             // NN*64 bf16
  ushort* h2b = r2b + (size_t)NN * 64;            // NN*64 bf16
  ushort* WF = h2b + (size_t)NN * 64;             // 32768 bf16
  float* poolP = (float*)(WF + 32768);            // 64*PSLICE*64 f32
  int* starts = (int*)(poolP + 64 * PSLICE * 64); // NN+1
  int* histG = starts + NN + 1;                   // NCHUNK*NBUCK
  int* relG = histG + NCHUNK * NBUCK;             // NCHUNK*NBUCK
  int* bucketTotal = relG + NCHUNK * NBUCK;       // NBUCK
  uint32_t* pairsG = (uint32_t*)(bucketTotal + NBUCK);  // EE
  int* esrc = (int*)(pairsG + EE);                // EE
  float* out = (float*)d_out;

  kfront<<<32 + XB_NB + NCHUNK, 256, 0, stream>>>(w1_rel, w1_root, w2_rel, w2_root,
                                                  x, dstI, WF, xb, histG);
  kscan2d<<<NBUCK, 512, 0, stream>>>(histG, relG, bucketTotal);
  kbinA2<<<NCHUNK, 256, 0, stream>>>(srcI, dstI, histG, relG, bucketTotal, pairsG);
  kbinB<<<NBUCK, 256, 0, stream>>>(pairsG, bucketTotal, starts, esrc);
  kgatherQ<<<(NN * 8 + 255) / 256, 256, 0, stream>>>(xb, starts, esrc, aggb);
  kfused<<<(NN + 127) / 128, 256, 0, stream>>>(xb, aggb, WF, b1_rel, yb, r2b);
  kgh2Q<<<(NN * 8 + 255) / 256, 256, 0, stream>>>(yb, starts, esrc, r2b, b2_rel, h2b);
  kpoolpart<<<64 * PSLICE, 256, 0, stream>>>(h2b, batch, poolP);
  kfinal3<<<64, 64, 0, stream>>>(poolP, batch, es_w1, es_b1, es_w2, es_b2, es_w3, es_b3,
                                 d_w1, d_b1, d_w2, d_b2, d_w3, d_b3, out);
}